// Round 3
// baseline (997.173 us; speedup 1.0000x reference)
//
#include <hip/hip_runtime.h>

// Conv2d 3x3 SAME, stride 1: x (16,64,256,256) f32, w (128,64,3,3), bias (128) -> out (16,128,256,256)
//
// V4: fp16 MFMA implicit-GEMM.
//  Pass 1a: w -> w_t[tap][s][cout][8ci] f16.
//  Pass 1b (NEW): x NCHW f32 -> NHWC f16 with NO LDS: each thread gathers 8 ci-planes
//    (8 coalesced loads, each instruction = 8 full 128B lines), packs half8, streams out.
//  Conv (NEW: 4 output rows/block): block = 128 cout x (4 rows x 64 cols), 4 waves (2co x 2px).
//    x tile [6 rows][66 cols][64 ci] f16 staged once, 16B-unit XOR swizzle (conflict-free b128).
//    Weights per-tap from L2 (288 KB/block now amortized over 2304 MFMAs).
//    mfma_f32_16x16x32_f16; D row=(lane>>4)*4+r (cout), col=lane&15 (pixel). Bias in acc init.

typedef _Float16 half8_t __attribute__((ext_vector_type(8)));
typedef float floatx4 __attribute__((ext_vector_type(4)));

#define HH 256
#define WW 256
#define CIN 64
#define COUT 128
#define NB 16

// ---------- pass 1a: weights OIHW f32 -> w_t[9][8][128][8] f16 ----------
__global__ void Conv2d_wprep_kernel(const float* __restrict__ w, _Float16* __restrict__ w_t) {
    int idx = blockIdx.x * 256 + threadIdx.x;
    if (idx >= 9 * 8 * 128 * 8) return;
    const int j = idx & 7, cout = (idx >> 3) & 127, s = (idx >> 10) & 7, t = idx >> 13;
    w_t[idx] = (_Float16)w[(cout * 64 + s * 8 + j) * 9 + t];
}

// ---------- pass 1b: x NCHW f32 -> NHWC f16, LDS-free transpose ----------
// grid (2, 256, 16); thread: u = tid&7 (ci-unit), colq = tid>>3 (0..31) -> 4 cols.
__global__ __launch_bounds__(256) void Conv2d_xprep_kernel(const float* __restrict__ x,
                                                           _Float16* __restrict__ x_h) {
    const int tid = threadIdx.x;
    const int u = tid & 7, colq = tid >> 3;
    const int n = blockIdx.z, h = blockIdx.y;
    const int col0 = blockIdx.x * 128 + colq * 4;

    float4 in[8];
#pragma unroll
    for (int j = 0; j < 8; ++j)
        in[j] = *(const float4*)(x + ((size_t)((n * 64 + u * 8 + j) * 256 + h) * 256) + col0);

    _Float16* dst = x_h + ((size_t)((n * 256 + h) * 256) + col0) * 64 + u * 8;
#pragma unroll
    for (int i = 0; i < 4; ++i) {
        half8_t hv;
        hv[0] = (_Float16)in[0].x; hv[1] = (_Float16)in[1].x;
        hv[2] = (_Float16)in[2].x; hv[3] = (_Float16)in[3].x;
        hv[4] = (_Float16)in[4].x; hv[5] = (_Float16)in[5].x;
        hv[6] = (_Float16)in[6].x; hv[7] = (_Float16)in[7].x;
        // rotate: use component i via reinterpret
        const float* f0 = (const float*)&in[0];
        half8_t hv2;
#pragma unroll
        for (int j = 0; j < 8; ++j) hv2[j] = (_Float16)((const float*)&in[j])[i];
        (void)hv;
        *(half8_t*)(dst + (size_t)i * 64) = hv2;
    }
}

// ---------- conv: fp16 MFMA, 4 rows x 64 cols x 128 cout per block ----------
__global__ __launch_bounds__(256, 2) void Conv2dManual_77695958385099_kernel(
    const _Float16* __restrict__ x_h, const _Float16* __restrict__ w_t,
    const float* __restrict__ bias, float* __restrict__ out) {
    __shared__ __align__(16) unsigned char xs[6 * 66 * 128];  // 50688 B
    const int tid = threadIdx.x;
    const int l = tid & 63, wv = tid >> 6;
    const int wc = wv >> 1, wp = wv & 1;         // cout-half, pixel-col-half
    const int g = l >> 4, ln = l & 15;
    const int ow0 = blockIdx.x * 64, oh0 = blockIdx.y * 4, n = blockIdx.z;

    // ---- stage x tile: rows oh0-1..oh0+4, cols ow0-1..ow0+64, 64 ci (f16) ----
    const int gstart = ow0 - 1;
    for (int u = tid; u < 6 * 528; u += 256) {    // 528 = 66 cols * 8 units
        const int row = u / 528, rem = u - row * 528;
        const int c = rem >> 3, s = rem & 7;
        const int gcol = gstart + c, ir = oh0 - 1 + row;
        int4 v = {0, 0, 0, 0};
        if ((unsigned)gcol < 256u && (unsigned)ir < 256u)
            v = *(const int4*)((const char*)x_h +
                               (size_t)((n * 256 + ir) * 256 + gcol) * 128 + s * 16);
        *(int4*)(xs + row * 8448 + c * 128 + ((s ^ (c & 7)) << 4)) = v;
    }

    // ---- per-lane LDS byte offsets: F[cg][kx][h] ----
    int F[2][3][2];
#pragma unroll
    for (int cg = 0; cg < 2; ++cg)
#pragma unroll
        for (int kx = 0; kx < 3; ++kx)
#pragma unroll
            for (int h = 0; h < 2; ++h) {
                const int c = wp * 32 + cg * 16 + kx + ln;
                const int s = 4 * h + g;
                F[cg][kx][h] = c * 128 + ((s ^ (c & 7)) << 4);
            }

    const char* wlane = (const char*)w_t + g * 2048 + (wc * 64 + ln) * 16;

    // ---- acc init with bias: D row = g*4+r -> cout = wc*64+cf*16+g*4+r ----
    floatx4 acc[4][8];
#pragma unroll
    for (int cf = 0; cf < 4; ++cf) {
        floatx4 b;
#pragma unroll
        for (int r = 0; r < 4; ++r) b[r] = bias[wc * 64 + cf * 16 + g * 4 + r];
#pragma unroll
        for (int pf = 0; pf < 8; ++pf) acc[cf][pf] = b;
    }

    __syncthreads();

    // ---- 9 taps x 2 K-steps, no barriers in loop ----
#pragma unroll
    for (int ky = 0; ky < 3; ++ky)
#pragma unroll
        for (int kx = 0; kx < 3; ++kx) {
            const char* wt = wlane + (ky * 3 + kx) * 16384;
#pragma unroll
            for (int h = 0; h < 2; ++h) {
                const half8_t a0 = *(const half8_t*)(wt + h * 8192 + 0 * 256);
                const half8_t a1 = *(const half8_t*)(wt + h * 8192 + 1 * 256);
                const half8_t a2 = *(const half8_t*)(wt + h * 8192 + 2 * 256);
                const half8_t a3 = *(const half8_t*)(wt + h * 8192 + 3 * 256);
#pragma unroll
                for (int rr = 0; rr < 4; ++rr) {
                    const int rowoff = (rr + ky) * 8448;
                    const half8_t b0 = *(const half8_t*)(xs + F[0][kx][h] + rowoff);
                    const half8_t b1 = *(const half8_t*)(xs + F[1][kx][h] + rowoff);
                    acc[0][rr * 2 + 0] = __builtin_amdgcn_mfma_f32_16x16x32_f16(a0, b0, acc[0][rr * 2 + 0], 0, 0, 0);
                    acc[0][rr * 2 + 1] = __builtin_amdgcn_mfma_f32_16x16x32_f16(a0, b1, acc[0][rr * 2 + 1], 0, 0, 0);
                    acc[1][rr * 2 + 0] = __builtin_amdgcn_mfma_f32_16x16x32_f16(a1, b0, acc[1][rr * 2 + 0], 0, 0, 0);
                    acc[1][rr * 2 + 1] = __builtin_amdgcn_mfma_f32_16x16x32_f16(a1, b1, acc[1][rr * 2 + 1], 0, 0, 0);
                    acc[2][rr * 2 + 0] = __builtin_amdgcn_mfma_f32_16x16x32_f16(a2, b0, acc[2][rr * 2 + 0], 0, 0, 0);
                    acc[2][rr * 2 + 1] = __builtin_amdgcn_mfma_f32_16x16x32_f16(a2, b1, acc[2][rr * 2 + 1], 0, 0, 0);
                    acc[3][rr * 2 + 0] = __builtin_amdgcn_mfma_f32_16x16x32_f16(a3, b0, acc[3][rr * 2 + 0], 0, 0, 0);
                    acc[3][rr * 2 + 1] = __builtin_amdgcn_mfma_f32_16x16x32_f16(a3, b1, acc[3][rr * 2 + 1], 0, 0, 0);
                }
            }
        }

    // ---- epilogue: store acc[cf][rr*2+cg][r] at (cout, oh0+rr, ow0+wp*32+cg*16+ln) ----
    float* obase = out + ((size_t)(n * 128 + wc * 64 + g * 4) * 256 + oh0) * 256 +
                   ow0 + wp * 32 + ln;
#pragma unroll
    for (int cf = 0; cf < 4; ++cf)
#pragma unroll
        for (int rr = 0; rr < 4; ++rr)
#pragma unroll
            for (int cg = 0; cg < 2; ++cg)
#pragma unroll
                for (int r = 0; r < 4; ++r)
                    obase[(size_t)(cf * 16 + r) * 65536 + rr * 256 + cg * 16] =
                        acc[cf][rr * 2 + cg][r];
}

// ---------- fallback (proven V2 fp32) if workspace too small ----------
__global__ __launch_bounds__(256) void Conv2d_fallback_kernel(
    const float* __restrict__ x, const float* __restrict__ w,
    const float* __restrict__ bias, float* __restrict__ out) {
    const int tx = threadIdx.x & 15, ty = threadIdx.x >> 4;
    const int ow0 = blockIdx.x * 64 + tx * 4;
    const int oh = blockIdx.y * 16 + ty;
    const int gg = blockIdx.z & 7, n = blockIdx.z >> 3;
    const int co = gg * 16;
    float acc[16][4];
#pragma unroll
    for (int c = 0; c < 16; ++c) {
        const float b = bias[co + c];
#pragma unroll
        for (int p = 0; p < 4; ++p) acc[c][p] = b;
    }
    const float* xn = x + (size_t)n * CIN * HH * WW;
    const float* wb = w + (size_t)co * CIN * 9;
    for (int ci = 0; ci < CIN; ++ci) {
        const float* xc = xn + (size_t)ci * HH * WW;
        float in[3][6];
#pragma unroll
        for (int ky = 0; ky < 3; ++ky) {
            const int iy = oh + ky - 1;
            if ((unsigned)iy < (unsigned)HH) {
                const float* row = xc + iy * WW;
                const float4 v = *(const float4*)(row + ow0);
                in[ky][1] = v.x; in[ky][2] = v.y; in[ky][3] = v.z; in[ky][4] = v.w;
                in[ky][0] = (ow0 > 0) ? row[ow0 - 1] : 0.0f;
                in[ky][5] = (ow0 < WW - 4) ? row[ow0 + 4] : 0.0f;
            } else {
#pragma unroll
                for (int j = 0; j < 6; ++j) in[ky][j] = 0.0f;
            }
        }
        const float* wc2 = wb + ci * 9;
#pragma unroll
        for (int c = 0; c < 16; ++c) {
            const float* wcc = wc2 + (size_t)c * CIN * 9;
#pragma unroll
            for (int ky = 0; ky < 3; ++ky)
#pragma unroll
                for (int kx = 0; kx < 3; ++kx) {
                    const float wv2 = wcc[ky * 3 + kx];
#pragma unroll
                    for (int p = 0; p < 4; ++p) acc[c][p] += in[ky][kx + p] * wv2;
                }
        }
    }
    const size_t hw = (size_t)HH * WW;
    float* ob = out + ((size_t)n * COUT + co) * hw + (size_t)oh * WW + ow0;
#pragma unroll
    for (int c = 0; c < 16; ++c) {
        float4 v;
        v.x = acc[c][0]; v.y = acc[c][1]; v.z = acc[c][2]; v.w = acc[c][3];
        *(float4*)(ob + (size_t)c * hw) = v;
    }
}

extern "C" void kernel_launch(void* const* d_in, const int* in_sizes, int n_in,
                              void* d_out, int out_size, void* d_ws, size_t ws_size,
                              hipStream_t stream) {
    const float* x = (const float*)d_in[0];
    const float* w = (const float*)d_in[1];
    const float* b = (const float*)d_in[2];
    float* out = (float*)d_out;

    const size_t xh_bytes = (size_t)NB * 256 * 256 * 64 * 2;  // 128 MiB
    const size_t wt_bytes = (size_t)9 * 8 * 128 * 8 * 2;      // 144 KiB

    if (ws_size >= xh_bytes + wt_bytes) {
        char* ws = (char*)d_ws;
        _Float16* x_h = (_Float16*)ws;
        _Float16* w_t = (_Float16*)(ws + xh_bytes);
        Conv2d_wprep_kernel<<<dim3(288), 256, 0, stream>>>(w, w_t);
        Conv2d_xprep_kernel<<<dim3(2, 256, 16), 256, 0, stream>>>(x, x_h);
        Conv2dManual_77695958385099_kernel<<<dim3(4, 64, 16), 256, 0, stream>>>(
            x_h, w_t, b, out);
    } else {
        dim3 grid(WW / 64, HH / 16, NB * (COUT / 16));
        Conv2d_fallback_kernel<<<grid, 256, 0, stream>>>(x, w, b, out);
    }
}

// Round 4
// 850.351 us; speedup vs baseline: 1.1727x; 1.1727x over previous
//
#include <hip/hip_runtime.h>

// Conv2d 3x3 SAME, stride 1: x (16,64,256,256) f32, w (128,64,3,3), bias (128) -> out (16,128,256,256)
//
// V5: persistent-strip fp16 MFMA implicit-GEMM.
//  - x -> padded NHWC f16 workspace x_p[n][258][258][64] (1-px zero border: staging has NO bounds checks).
//  - conv: 256 blocks (4 strips x 4 bands x 16 n) x 512 thr (8 waves = 4 cout-quarters x 2 col-halves).
//    Loop 16 iters of 4 output rows. Double-buffered 6x66x64ci LDS tile staged with
//    global_load_lds (16B), linear LDS dest + inverse-swizzled global source; ds_read side
//    uses the V4-verified XOR swizzle F = c*128 + ((s^(c&7))<<4)  -> 0 bank conflicts.
//  - Weights persistent in registers: A[2][2][9] half8 per wave (loaded once) -> no L2 re-reads.
//  - Non-temporal output stores (write-once stream; keeps x_p L3-resident).

typedef _Float16 half8_t __attribute__((ext_vector_type(8)));
typedef float floatx4 __attribute__((ext_vector_type(4)));

#define HH 256
#define WW 256
#define CIN 64
#define COUT 128
#define NB 16

#define XP_RSTRIDE   16512            // halves per padded row (258*64)
#define XP_NSTRIDE   4260096          // halves per n (258*16512)
#define XP_RSTRIDE_B 33024            // bytes per padded row
#define ROW_LDS      8448             // bytes per LDS tile row (66 cols * 128 B)
#define TILE_BYTES   50688            // 6 * ROW_LDS
#define TILE_UNITS   3168             // 6 * 528 16B-units

__device__ inline void gload_lds16(const void* g, void* l) {
    __builtin_amdgcn_global_load_lds(
        (const __attribute__((address_space(1))) unsigned int*)g,
        (__attribute__((address_space(3))) unsigned int*)l, 16, 0, 0);
}

// ---------- pass 1a: weights OIHW f32 -> w_t[9][8][128][8] f16 ----------
__global__ void Conv2d_wprep_kernel(const float* __restrict__ w, _Float16* __restrict__ w_t) {
    int idx = blockIdx.x * 256 + threadIdx.x;
    if (idx >= 9 * 8 * 128 * 8) return;
    const int j = idx & 7, cout = (idx >> 3) & 127, s = (idx >> 10) & 7, t = idx >> 13;
    w_t[idx] = (_Float16)w[(cout * 64 + s * 8 + j) * 9 + t];
}

// ---------- pass 1b-zero: zero the 1-px border of x_p ----------
__global__ void Conv2d_xpad_zero_kernel(_Float16* __restrict__ xp) {
    const int idx = blockIdx.x * 256 + threadIdx.x;   // 16B units, 8224 per n
    const int n = blockIdx.y;
    if (idx >= 8224) return;
    size_t off;  // in halves
    if (idx < 2064)      off = (size_t)idx * 8;                                    // row 0
    else if (idx < 4128) off = (size_t)257 * XP_RSTRIDE + (size_t)(idx - 2064) * 8; // row 257
    else if (idx < 6176) { const int t = idx - 4128;                               // col 0
        off = (size_t)(1 + (t >> 3)) * XP_RSTRIDE + (size_t)(t & 7) * 8; }
    else { const int t = idx - 6176;                                               // col 257
        off = (size_t)(1 + (t >> 3)) * XP_RSTRIDE + 257 * 64 + (size_t)(t & 7) * 8; }
    int4 z = {0, 0, 0, 0};
    *(int4*)(xp + (size_t)n * XP_NSTRIDE + off) = z;
}

// ---------- pass 1b: x NCHW f32 -> padded NHWC f16 (LDS-free transpose) ----------
__global__ __launch_bounds__(256) void Conv2d_xprep_kernel(const float* __restrict__ x,
                                                           _Float16* __restrict__ xp) {
    const int tid = threadIdx.x;
    const int u = tid & 7, colq = tid >> 3;
    const int n = blockIdx.z, h = blockIdx.y;
    const int col0 = blockIdx.x * 128 + colq * 4;

    float4 in[8];
#pragma unroll
    for (int j = 0; j < 8; ++j)
        in[j] = *(const float4*)(x + ((size_t)((n * 64 + u * 8 + j) * 256 + h) * 256) + col0);

    _Float16* dst = xp + (size_t)n * XP_NSTRIDE + (size_t)(h + 1) * XP_RSTRIDE +
                    (size_t)(col0 + 1) * 64 + u * 8;
#pragma unroll
    for (int i = 0; i < 4; ++i) {
        half8_t hv;
#pragma unroll
        for (int j = 0; j < 8; ++j) hv[j] = (_Float16)((const float*)&in[j])[i];
        *(half8_t*)(dst + (size_t)i * 64) = hv;
    }
}

// ---------- conv: persistent strips, fp16 MFMA ----------
__global__ __launch_bounds__(512, 2) void Conv2dManual_77695958385099_kernel(
    const _Float16* __restrict__ xp, const _Float16* __restrict__ w_t,
    const float* __restrict__ bias, float* __restrict__ out) {
    __shared__ __align__(16) unsigned char xs[2 * TILE_BYTES];  // 101376 B
    const int tid = threadIdx.x;
    const int l = tid & 63, wv = tid >> 6;
    const int wq = wv >> 1;          // cout quarter (0..3) -> couts wq*32..+31
    const int wp = wv & 1;           // col half
    const int g = l >> 4, ln = l & 15;
    const int ow0 = blockIdx.x * 64;
    const int band = blockIdx.y;     // rows band*64..+63
    const int n = blockIdx.z;

    // ---- persistent weight fragments: A[cf][h][tap], 36 x half8 ----
    const char* wl = (const char*)w_t + g * 2048 + (wq * 32 + ln) * 16;
    half8_t A[2][2][9];
#pragma unroll
    for (int cf = 0; cf < 2; ++cf)
#pragma unroll
        for (int h = 0; h < 2; ++h)
#pragma unroll
            for (int tp = 0; tp < 9; ++tp)
                A[cf][h][tp] = *(const half8_t*)(wl + cf * 256 + h * 8192 + tp * 16384);

    floatx4 bvv[2];
#pragma unroll
    for (int cf = 0; cf < 2; ++cf)
#pragma unroll
        for (int r = 0; r < 4; ++r) bvv[cf][r] = bias[wq * 32 + cf * 16 + g * 4 + r];

    // tile byte base for iter it: xbase + (band*64 + it*4) * XP_RSTRIDE_B  (+row*XP_RSTRIDE_B)
    const char* xbase = (const char*)xp + (size_t)n * XP_NSTRIDE * 2 + (size_t)ow0 * 128;

#define STAGE(BUFSEL, IT)                                                              \
    {                                                                                  \
        const char* gt = xbase + (size_t)(band * 64 + (IT) * 4) * XP_RSTRIDE_B;        \
        const unsigned lb = (BUFSEL) * TILE_BYTES;                                     \
        _Pragma("unroll")                                                              \
        for (int p = 0; p < 6; ++p) {                                                  \
            const int u = p * 512 + tid;                                               \
            int row = (p * 512) / 528;                                                 \
            if (u >= (row + 1) * 528) row++;                                           \
            const int rem = u - row * 528;                                             \
            const int c = rem >> 3, s = rem & 7;                                       \
            gload_lds16(gt + (size_t)row * XP_RSTRIDE_B + c * 128 +                    \
                            (((s ^ (c & 7))) << 4),                                    \
                        xs + lb + ((unsigned)(p * 512 + (tid & ~63)) << 4));           \
        }                                                                              \
        if (tid < 96) {                                                                \
            const int rem = 432 + tid;                                                 \
            const int c = rem >> 3, s = rem & 7;                                       \
            const int4 v = *(const int4*)(gt + (size_t)5 * XP_RSTRIDE_B + c * 128 +    \
                                          ((s ^ (c & 7)) << 4));                       \
            *(int4*)(xs + lb + (unsigned)(3072 + tid) * 16) = v;                       \
        }                                                                              \
    }

    STAGE(0, 0);
    __syncthreads();

    int cur = 0;
    for (int it = 0; it < 16; ++it) {
        if (it < 15) STAGE(cur ^ 1, it + 1);

        floatx4 acc[2][8];
#pragma unroll
        for (int cf = 0; cf < 2; ++cf)
#pragma unroll
            for (int pf = 0; pf < 8; ++pf) acc[cf][pf] = bvv[cf];

        const unsigned char* bb = xs + cur * TILE_BYTES;
#pragma unroll
        for (int kx = 0; kx < 3; ++kx)
#pragma unroll
            for (int h = 0; h < 2; ++h)
#pragma unroll
                for (int cg = 0; cg < 2; ++cg) {
                    const int c = wp * 32 + cg * 16 + kx + ln;
                    const unsigned char* bp = bb + c * 128 + (((4 * h + g) ^ (c & 7)) << 4);
#pragma unroll
                    for (int t = 0; t < 6; ++t) {
                        const half8_t bt = *(const half8_t*)(bp + t * ROW_LDS);
#pragma unroll
                        for (int ky = 0; ky < 3; ++ky) {
                            const int rr = t - ky;
                            if (rr >= 0 && rr < 4) {
                                acc[0][rr * 2 + cg] = __builtin_amdgcn_mfma_f32_16x16x32_f16(
                                    A[0][h][ky * 3 + kx], bt, acc[0][rr * 2 + cg], 0, 0, 0);
                                acc[1][rr * 2 + cg] = __builtin_amdgcn_mfma_f32_16x16x32_f16(
                                    A[1][h][ky * 3 + kx], bt, acc[1][rr * 2 + cg], 0, 0, 0);
                            }
                        }
                    }
                }

        // ---- epilogue: nontemporal stores (write-once stream) ----
        float* ob = out + ((size_t)(n * 128 + wq * 32 + g * 4)) * 65536 +
                    (size_t)(band * 64 + it * 4) * 256 + ow0 + wp * 32 + ln;
#pragma unroll
        for (int cf = 0; cf < 2; ++cf)
#pragma unroll
            for (int rr = 0; rr < 4; ++rr)
#pragma unroll
                for (int cg = 0; cg < 2; ++cg)
#pragma unroll
                    for (int r = 0; r < 4; ++r)
                        __builtin_nontemporal_store(
                            acc[cf][rr * 2 + cg][r],
                            ob + (size_t)(cf * 16 + r) * 65536 + rr * 256 + cg * 16);

        __syncthreads();
        cur ^= 1;
    }
#undef STAGE
}

// ---------- fallback (proven V2 fp32) if workspace too small ----------
__global__ __launch_bounds__(256) void Conv2d_fallback_kernel(
    const float* __restrict__ x, const float* __restrict__ w,
    const float* __restrict__ bias, float* __restrict__ out) {
    const int tx = threadIdx.x & 15, ty = threadIdx.x >> 4;
    const int ow0 = blockIdx.x * 64 + tx * 4;
    const int oh = blockIdx.y * 16 + ty;
    const int gg = blockIdx.z & 7, n = blockIdx.z >> 3;
    const int co = gg * 16;
    float acc[16][4];
#pragma unroll
    for (int c = 0; c < 16; ++c) {
        const float b = bias[co + c];
#pragma unroll
        for (int p = 0; p < 4; ++p) acc[c][p] = b;
    }
    const float* xn = x + (size_t)n * CIN * HH * WW;
    const float* wb = w + (size_t)co * CIN * 9;
    for (int ci = 0; ci < CIN; ++ci) {
        const float* xc = xn + (size_t)ci * HH * WW;
        float in[3][6];
#pragma unroll
        for (int ky = 0; ky < 3; ++ky) {
            const int iy = oh + ky - 1;
            if ((unsigned)iy < (unsigned)HH) {
                const float* row = xc + iy * WW;
                const float4 v = *(const float4*)(row + ow0);
                in[ky][1] = v.x; in[ky][2] = v.y; in[ky][3] = v.z; in[ky][4] = v.w;
                in[ky][0] = (ow0 > 0) ? row[ow0 - 1] : 0.0f;
                in[ky][5] = (ow0 < WW - 4) ? row[ow0 + 4] : 0.0f;
            } else {
#pragma unroll
                for (int j = 0; j < 6; ++j) in[ky][j] = 0.0f;
            }
        }
        const float* wc2 = wb + ci * 9;
#pragma unroll
        for (int c = 0; c < 16; ++c) {
            const float* wcc = wc2 + (size_t)c * CIN * 9;
#pragma unroll
            for (int ky = 0; ky < 3; ++ky)
#pragma unroll
                for (int kx = 0; kx < 3; ++kx) {
                    const float wv2 = wcc[ky * 3 + kx];
#pragma unroll
                    for (int p = 0; p < 4; ++p) acc[c][p] += in[ky][kx + p] * wv2;
                }
        }
    }
    const size_t hw = (size_t)HH * WW;
    float* ob = out + ((size_t)n * COUT + co) * hw + (size_t)oh * WW + ow0;
#pragma unroll
    for (int c = 0; c < 16; ++c) {
        float4 v;
        v.x = acc[c][0]; v.y = acc[c][1]; v.z = acc[c][2]; v.w = acc[c][3];
        *(float4*)(ob + (size_t)c * hw) = v;
    }
}

extern "C" void kernel_launch(void* const* d_in, const int* in_sizes, int n_in,
                              void* d_out, int out_size, void* d_ws, size_t ws_size,
                              hipStream_t stream) {
    const float* x = (const float*)d_in[0];
    const float* w = (const float*)d_in[1];
    const float* b = (const float*)d_in[2];
    float* out = (float*)d_out;

    const size_t xp_bytes = (size_t)NB * XP_NSTRIDE * 2;      // 136.3 MB
    const size_t wt_bytes = (size_t)9 * 8 * 128 * 8 * 2;      // 144 KiB

    if (ws_size >= xp_bytes + wt_bytes) {
        char* ws = (char*)d_ws;
        _Float16* xp = (_Float16*)ws;
        _Float16* w_t = (_Float16*)(ws + xp_bytes);
        Conv2d_wprep_kernel<<<dim3(288), 256, 0, stream>>>(w, w_t);
        Conv2d_xpad_zero_kernel<<<dim3(33, 16), 256, 0, stream>>>(xp);
        Conv2d_xprep_kernel<<<dim3(2, 256, 16), 256, 0, stream>>>(x, xp);
        Conv2dManual_77695958385099_kernel<<<dim3(4, 4, 16), 512, 0, stream>>>(
            xp, w_t, b, out);
    } else {
        dim3 grid(WW / 64, HH / 16, NB * (COUT / 16));
        Conv2d_fallback_kernel<<<grid, 256, 0, stream>>>(x, w, b, out);
    }
}

// Round 5
// 791.140 us; speedup vs baseline: 1.2604x; 1.0748x over previous
//
#include <hip/hip_runtime.h>

// Conv2d 3x3 SAME, stride 1: x (16,64,256,256) f32, w (128,64,3,3), bias (128) -> out (16,128,256,256)
//
// V6: persistent-strip fp16 MFMA implicit-GEMM.
//  - x -> padded NHWC f16 workspace x_p[n][258][258][64] (1-px zero border: staging has NO bounds checks).
//  - conv: 256 blocks (4 strips x 4 bands x 16 n) x 512 thr (8 waves = 4 cout-quarters x 2 col-halves).
//    Loop 16 iters of 4 output rows. Double-buffered 6x66x64ci LDS tile staged with
//    global_load_lds (16B), linear LDS dest + inverse-swizzled global source; ds_read side
//    uses the verified XOR swizzle F = c*128 + ((s^(c&7))<<4)  -> 0 bank conflicts.
//  - Weights persistent in registers: A[2][2][9] half8 per wave (loaded once) -> no L2 re-reads.
//  - V6 CHANGE: epilogue stores moved AFTER the per-iter barrier. The barrier's vmcnt(0)
//    no longer drains the current iter's 32k NT stores to HBM-ack depth; stores get a full
//    iteration of compute to retire. (V5 serialized {compute -> full HBM store drain} every
//    iter with 1 block/CU -> ~85us structural dead time.)
//  - Store order: cg innermost (adjacent 64B halves of each 128B line).

typedef _Float16 half8_t __attribute__((ext_vector_type(8)));
typedef float floatx4 __attribute__((ext_vector_type(4)));

#define HH 256
#define WW 256
#define CIN 64
#define COUT 128
#define NB 16

#define XP_RSTRIDE   16512            // halves per padded row (258*64)
#define XP_NSTRIDE   4260096          // halves per n (258*16512)
#define XP_RSTRIDE_B 33024            // bytes per padded row
#define ROW_LDS      8448             // bytes per LDS tile row (66 cols * 128 B)
#define TILE_BYTES   50688            // 6 * ROW_LDS
#define TILE_UNITS   3168             // 6 * 528 16B-units

__device__ inline void gload_lds16(const void* g, void* l) {
    __builtin_amdgcn_global_load_lds(
        (const __attribute__((address_space(1))) unsigned int*)g,
        (__attribute__((address_space(3))) unsigned int*)l, 16, 0, 0);
}

// ---------- pass 1a: weights OIHW f32 -> w_t[9][8][128][8] f16 ----------
__global__ void Conv2d_wprep_kernel(const float* __restrict__ w, _Float16* __restrict__ w_t) {
    int idx = blockIdx.x * 256 + threadIdx.x;
    if (idx >= 9 * 8 * 128 * 8) return;
    const int j = idx & 7, cout = (idx >> 3) & 127, s = (idx >> 10) & 7, t = idx >> 13;
    w_t[idx] = (_Float16)w[(cout * 64 + s * 8 + j) * 9 + t];
}

// ---------- pass 1b-zero: zero the 1-px border of x_p ----------
__global__ void Conv2d_xpad_zero_kernel(_Float16* __restrict__ xp) {
    const int idx = blockIdx.x * 256 + threadIdx.x;   // 16B units, 8224 per n
    const int n = blockIdx.y;
    if (idx >= 8224) return;
    size_t off;  // in halves
    if (idx < 2064)      off = (size_t)idx * 8;                                    // row 0
    else if (idx < 4128) off = (size_t)257 * XP_RSTRIDE + (size_t)(idx - 2064) * 8; // row 257
    else if (idx < 6176) { const int t = idx - 4128;                               // col 0
        off = (size_t)(1 + (t >> 3)) * XP_RSTRIDE + (size_t)(t & 7) * 8; }
    else { const int t = idx - 6176;                                               // col 257
        off = (size_t)(1 + (t >> 3)) * XP_RSTRIDE + 257 * 64 + (size_t)(t & 7) * 8; }
    int4 z = {0, 0, 0, 0};
    *(int4*)(xp + (size_t)n * XP_NSTRIDE + off) = z;
}

// ---------- pass 1b: x NCHW f32 -> padded NHWC f16 (LDS-free transpose) ----------
__global__ __launch_bounds__(256) void Conv2d_xprep_kernel(const float* __restrict__ x,
                                                           _Float16* __restrict__ xp) {
    const int tid = threadIdx.x;
    const int u = tid & 7, colq = tid >> 3;
    const int n = blockIdx.z, h = blockIdx.y;
    const int col0 = blockIdx.x * 128 + colq * 4;

    float4 in[8];
#pragma unroll
    for (int j = 0; j < 8; ++j)
        in[j] = *(const float4*)(x + ((size_t)((n * 64 + u * 8 + j) * 256 + h) * 256) + col0);

    _Float16* dst = xp + (size_t)n * XP_NSTRIDE + (size_t)(h + 1) * XP_RSTRIDE +
                    (size_t)(col0 + 1) * 64 + u * 8;
#pragma unroll
    for (int i = 0; i < 4; ++i) {
        half8_t hv;
#pragma unroll
        for (int j = 0; j < 8; ++j) hv[j] = (_Float16)((const float*)&in[j])[i];
        *(half8_t*)(dst + (size_t)i * 64) = hv;
    }
}

// ---------- conv: persistent strips, fp16 MFMA ----------
__global__ __launch_bounds__(512, 2) void Conv2dManual_77695958385099_kernel(
    const _Float16* __restrict__ xp, const _Float16* __restrict__ w_t,
    const float* __restrict__ bias, float* __restrict__ out) {
    __shared__ __align__(16) unsigned char xs[2 * TILE_BYTES];  // 101376 B
    const int tid = threadIdx.x;
    const int l = tid & 63, wv = tid >> 6;
    const int wq = wv >> 1;          // cout quarter (0..3) -> couts wq*32..+31
    const int wp = wv & 1;           // col half
    const int g = l >> 4, ln = l & 15;
    const int ow0 = blockIdx.x * 64;
    const int band = blockIdx.y;     // rows band*64..+63
    const int n = blockIdx.z;

    // ---- persistent weight fragments: A[cf][h][tap], 36 x half8 ----
    const char* wl = (const char*)w_t + g * 2048 + (wq * 32 + ln) * 16;
    half8_t A[2][2][9];
#pragma unroll
    for (int cf = 0; cf < 2; ++cf)
#pragma unroll
        for (int h = 0; h < 2; ++h)
#pragma unroll
            for (int tp = 0; tp < 9; ++tp)
                A[cf][h][tp] = *(const half8_t*)(wl + cf * 256 + h * 8192 + tp * 16384);

    floatx4 bvv[2];
#pragma unroll
    for (int cf = 0; cf < 2; ++cf)
#pragma unroll
        for (int r = 0; r < 4; ++r) bvv[cf][r] = bias[wq * 32 + cf * 16 + g * 4 + r];

    const char* xbase = (const char*)xp + (size_t)n * XP_NSTRIDE * 2 + (size_t)ow0 * 128;

#define STAGE(BUFSEL, IT)                                                              \
    {                                                                                  \
        const char* gt = xbase + (size_t)(band * 64 + (IT) * 4) * XP_RSTRIDE_B;        \
        const unsigned lb = (BUFSEL) * TILE_BYTES;                                     \
        _Pragma("unroll")                                                              \
        for (int p = 0; p < 6; ++p) {                                                  \
            const int u = p * 512 + tid;                                               \
            int row = (p * 512) / 528;                                                 \
            if (u >= (row + 1) * 528) row++;                                           \
            const int rem = u - row * 528;                                             \
            const int c = rem >> 3, s = rem & 7;                                       \
            gload_lds16(gt + (size_t)row * XP_RSTRIDE_B + c * 128 +                    \
                            (((s ^ (c & 7))) << 4),                                    \
                        xs + lb + ((unsigned)(p * 512 + (tid & ~63)) << 4));           \
        }                                                                              \
        if (tid < 96) {                                                                \
            const int rem = 432 + tid;                                                 \
            const int c = rem >> 3, s = rem & 7;                                       \
            const int4 v = *(const int4*)(gt + (size_t)5 * XP_RSTRIDE_B + c * 128 +    \
                                          ((s ^ (c & 7)) << 4));                       \
            *(int4*)(xs + lb + (unsigned)(3072 + tid) * 16) = v;                       \
        }                                                                              \
    }

    STAGE(0, 0);
    __syncthreads();

    int cur = 0;
    for (int it = 0; it < 16; ++it) {
        if (it < 15) STAGE(cur ^ 1, it + 1);

        floatx4 acc[2][8];
#pragma unroll
        for (int cf = 0; cf < 2; ++cf)
#pragma unroll
            for (int pf = 0; pf < 8; ++pf) acc[cf][pf] = bvv[cf];

        const unsigned char* bb = xs + cur * TILE_BYTES;
#pragma unroll
        for (int kx = 0; kx < 3; ++kx)
#pragma unroll
            for (int h = 0; h < 2; ++h)
#pragma unroll
                for (int cg = 0; cg < 2; ++cg) {
                    const int c = wp * 32 + cg * 16 + kx + ln;
                    const unsigned char* bp = bb + c * 128 + (((4 * h + g) ^ (c & 7)) << 4);
#pragma unroll
                    for (int t = 0; t < 6; ++t) {
                        const half8_t bt = *(const half8_t*)(bp + t * ROW_LDS);
#pragma unroll
                        for (int ky = 0; ky < 3; ++ky) {
                            const int rr = t - ky;
                            if (rr >= 0 && rr < 4) {
                                acc[0][rr * 2 + cg] = __builtin_amdgcn_mfma_f32_16x16x32_f16(
                                    A[0][h][ky * 3 + kx], bt, acc[0][rr * 2 + cg], 0, 0, 0);
                                acc[1][rr * 2 + cg] = __builtin_amdgcn_mfma_f32_16x16x32_f16(
                                    A[1][h][ky * 3 + kx], bt, acc[1][rr * 2 + cg], 0, 0, 0);
                            }
                        }
                    }
                }

        // Barrier BEFORE stores: vmcnt(0) here drains next-tile gloads + the
        // (iteration-old, already retired) previous stores — not this iter's.
        __syncthreads();

        // ---- epilogue: NT stores issued post-barrier, retire under next compute ----
        float* ob = out + ((size_t)(n * 128 + wq * 32 + g * 4)) * 65536 +
                    (size_t)(band * 64 + it * 4) * 256 + ow0 + wp * 32 + ln;
#pragma unroll
        for (int cf = 0; cf < 2; ++cf)
#pragma unroll
            for (int rr = 0; rr < 4; ++rr)
#pragma unroll
                for (int r = 0; r < 4; ++r)
#pragma unroll
                    for (int cg = 0; cg < 2; ++cg)   // cg innermost: 64B halves adjacent
                        __builtin_nontemporal_store(
                            acc[cf][rr * 2 + cg][r],
                            ob + (size_t)(cf * 16 + r) * 65536 + rr * 256 + cg * 16);

        cur ^= 1;
    }
#undef STAGE
}

// ---------- fallback (proven V2 fp32) if workspace too small ----------
__global__ __launch_bounds__(256) void Conv2d_fallback_kernel(
    const float* __restrict__ x, const float* __restrict__ w,
    const float* __restrict__ bias, float* __restrict__ out) {
    const int tx = threadIdx.x & 15, ty = threadIdx.x >> 4;
    const int ow0 = blockIdx.x * 64 + tx * 4;
    const int oh = blockIdx.y * 16 + ty;
    const int gg = blockIdx.z & 7, n = blockIdx.z >> 3;
    const int co = gg * 16;
    float acc[16][4];
#pragma unroll
    for (int c = 0; c < 16; ++c) {
        const float b = bias[co + c];
#pragma unroll
        for (int p = 0; p < 4; ++p) acc[c][p] = b;
    }
    const float* xn = x + (size_t)n * CIN * HH * WW;
    const float* wb = w + (size_t)co * CIN * 9;
    for (int ci = 0; ci < CIN; ++ci) {
        const float* xc = xn + (size_t)ci * HH * WW;
        float in[3][6];
#pragma unroll
        for (int ky = 0; ky < 3; ++ky) {
            const int iy = oh + ky - 1;
            if ((unsigned)iy < (unsigned)HH) {
                const float* row = xc + iy * WW;
                const float4 v = *(const float4*)(row + ow0);
                in[ky][1] = v.x; in[ky][2] = v.y; in[ky][3] = v.z; in[ky][4] = v.w;
                in[ky][0] = (ow0 > 0) ? row[ow0 - 1] : 0.0f;
                in[ky][5] = (ow0 < WW - 4) ? row[ow0 + 4] : 0.0f;
            } else {
#pragma unroll
                for (int j = 0; j < 6; ++j) in[ky][j] = 0.0f;
            }
        }
        const float* wc2 = wb + ci * 9;
#pragma unroll
        for (int c = 0; c < 16; ++c) {
            const float* wcc = wc2 + (size_t)c * CIN * 9;
#pragma unroll
            for (int ky = 0; ky < 3; ++ky)
#pragma unroll
                for (int kx = 0; kx < 3; ++kx) {
                    const float wv2 = wcc[ky * 3 + kx];
#pragma unroll
                    for (int p = 0; p < 4; ++p) acc[c][p] += in[ky][kx + p] * wv2;
                }
        }
    }
    const size_t hw = (size_t)HH * WW;
    float* ob = out + ((size_t)n * COUT + co) * hw + (size_t)oh * WW + ow0;
#pragma unroll
    for (int c = 0; c < 16; ++c) {
        float4 v;
        v.x = acc[c][0]; v.y = acc[c][1]; v.z = acc[c][2]; v.w = acc[c][3];
        *(float4*)(ob + (size_t)c * hw) = v;
    }
}

extern "C" void kernel_launch(void* const* d_in, const int* in_sizes, int n_in,
                              void* d_out, int out_size, void* d_ws, size_t ws_size,
                              hipStream_t stream) {
    const float* x = (const float*)d_in[0];
    const float* w = (const float*)d_in[1];
    const float* b = (const float*)d_in[2];
    float* out = (float*)d_out;

    const size_t xp_bytes = (size_t)NB * XP_NSTRIDE * 2;      // 136.3 MB
    const size_t wt_bytes = (size_t)9 * 8 * 128 * 8 * 2;      // 144 KiB

    if (ws_size >= xp_bytes + wt_bytes) {
        char* ws = (char*)d_ws;
        _Float16* xp = (_Float16*)ws;
        _Float16* w_t = (_Float16*)(ws + xp_bytes);
        Conv2d_wprep_kernel<<<dim3(288), 256, 0, stream>>>(w, w_t);
        Conv2d_xpad_zero_kernel<<<dim3(33, 16), 256, 0, stream>>>(xp);
        Conv2d_xprep_kernel<<<dim3(2, 256, 16), 256, 0, stream>>>(x, xp);
        Conv2dManual_77695958385099_kernel<<<dim3(4, 4, 16), 512, 0, stream>>>(
            xp, w_t, b, out);
    } else {
        dim3 grid(WW / 64, HH / 16, NB * (COUT / 16));
        Conv2d_fallback_kernel<<<grid, 256, 0, stream>>>(x, w, b, out);
    }
}

// Round 6
// 775.791 us; speedup vs baseline: 1.2854x; 1.0198x over previous
//
#include <hip/hip_runtime.h>

// Conv2d 3x3 SAME, stride 1: x (16,64,256,256) f32, w (128,64,3,3), bias (128) -> out (16,128,256,256)
//
// V7: fp16 MFMA implicit-GEMM, register-persistent weights + counted-vmcnt pipeline.
//  - x -> padded NHWC f16 workspace x_p[n][258][258][64] (1-px zero border).
//  - conv: 256 blocks (4 strips x 4 bands x 16 n) x 512 thr. NEW wave split: 8 waves x 16 couts
//    each; every wave computes the whole 64col x 4row tile for its couts.
//    Per-wave A = 18 half8 = 72 VGPR  -> fits with acc(64) under the 256 cap, so the
//    compiler keeps weights register-resident (V6's 36-frag/144-VGPR layout was silently
//    rematerialized from L2 every iter: VGPR_Count=128 proved it; ~41k cyc/iter of L2 A-traffic).
//  - Raw s_barrier + counted s_waitcnt vmcnt(16): staging loads (issued first) are drained,
//    the 16 NT stores/iter stay in flight a full iteration (no vmcnt(0) drain per iter).
//  - Epilogue via per-wave LDS scratch (stride 68: 2-way-free banks): NT dwordx4 stores,
//    16 lanes = 256B contiguous -> full 128B lines per instruction.
//  - Staging/swizzle/MFMA mappings bit-identical to verified V4/V6:
//    LDS unit swizzle ((s^(c&7))<<4), F = c*128 + (((4h+g)^(c&7))<<4), D row=g*4+r, col=ln.

typedef _Float16 half8_t __attribute__((ext_vector_type(8)));
typedef float floatx4 __attribute__((ext_vector_type(4)));

#define HH 256
#define WW 256
#define CIN 64
#define COUT 128
#define NB 16

#define XP_RSTRIDE   16512            // halves per padded row (258*64)
#define XP_NSTRIDE   4260096          // halves per n (258*16512)
#define XP_RSTRIDE_B 33024            // bytes per padded row
#define ROW_LDS      8448             // bytes per LDS tile row (66 cols * 128 B)
#define TILE_BYTES   50688            // 6 * ROW_LDS

__device__ inline void gload_lds16(const void* g, void* l) {
    __builtin_amdgcn_global_load_lds(
        (const __attribute__((address_space(1))) unsigned int*)g,
        (__attribute__((address_space(3))) unsigned int*)l, 16, 0, 0);
}

// ---------- pass 1a: weights OIHW f32 -> w_t[9][8][128][8] f16 ----------
__global__ void Conv2d_wprep_kernel(const float* __restrict__ w, _Float16* __restrict__ w_t) {
    int idx = blockIdx.x * 256 + threadIdx.x;
    if (idx >= 9 * 8 * 128 * 8) return;
    const int j = idx & 7, cout = (idx >> 3) & 127, s = (idx >> 10) & 7, t = idx >> 13;
    w_t[idx] = (_Float16)w[(cout * 64 + s * 8 + j) * 9 + t];
}

// ---------- pass 1b-zero: zero the 1-px border of x_p ----------
__global__ void Conv2d_xpad_zero_kernel(_Float16* __restrict__ xp) {
    const int idx = blockIdx.x * 256 + threadIdx.x;   // 16B units, 8224 per n
    const int n = blockIdx.y;
    if (idx >= 8224) return;
    size_t off;  // in halves
    if (idx < 2064)      off = (size_t)idx * 8;                                    // row 0
    else if (idx < 4128) off = (size_t)257 * XP_RSTRIDE + (size_t)(idx - 2064) * 8; // row 257
    else if (idx < 6176) { const int t = idx - 4128;                               // col 0
        off = (size_t)(1 + (t >> 3)) * XP_RSTRIDE + (size_t)(t & 7) * 8; }
    else { const int t = idx - 6176;                                               // col 257
        off = (size_t)(1 + (t >> 3)) * XP_RSTRIDE + 257 * 64 + (size_t)(t & 7) * 8; }
    int4 z = {0, 0, 0, 0};
    *(int4*)(xp + (size_t)n * XP_NSTRIDE + off) = z;
}

// ---------- pass 1b: x NCHW f32 -> padded NHWC f16 (LDS-free transpose) ----------
__global__ __launch_bounds__(256) void Conv2d_xprep_kernel(const float* __restrict__ x,
                                                           _Float16* __restrict__ xp) {
    const int tid = threadIdx.x;
    const int u = tid & 7, colq = tid >> 3;
    const int n = blockIdx.z, h = blockIdx.y;
    const int col0 = blockIdx.x * 128 + colq * 4;

    float4 in[8];
#pragma unroll
    for (int j = 0; j < 8; ++j)
        in[j] = *(const float4*)(x + ((size_t)((n * 64 + u * 8 + j) * 256 + h) * 256) + col0);

    _Float16* dst = xp + (size_t)n * XP_NSTRIDE + (size_t)(h + 1) * XP_RSTRIDE +
                    (size_t)(col0 + 1) * 64 + u * 8;
#pragma unroll
    for (int i = 0; i < 4; ++i) {
        half8_t hv;
#pragma unroll
        for (int j = 0; j < 8; ++j) hv[j] = (_Float16)((const float*)&in[j])[i];
        *(half8_t*)(dst + (size_t)i * 64) = hv;
    }
}

// ---------- conv: persistent strips, register-resident weights ----------
__global__ __launch_bounds__(512, 2) void Conv2dManual_77695958385099_kernel(
    const _Float16* __restrict__ xp, const _Float16* __restrict__ w_t,
    const float* __restrict__ bias, float* __restrict__ out) {
    __shared__ __align__(16) unsigned char xs[2 * TILE_BYTES];  // 101376 B
    __shared__ __align__(16) float esc[8][1088];                // 34816 B (16 couts x 68 pad)
    const int tid = threadIdx.x;
    const int l = tid & 63, wvid = tid >> 6;   // wave -> couts wvid*16 .. +15
    const int g = l >> 4, ln = l & 15;
    const int ow0 = blockIdx.x * 64;
    const int band = blockIdx.y;               // rows band*64..+63
    const int n = blockIdx.z;

    // ---- persistent weights: A[h][tap], 18 x half8 = 72 VGPR ----
    const char* wl = (const char*)w_t + g * 2048 + (wvid * 16 + ln) * 16;
    half8_t A[2][9];
#pragma unroll
    for (int h = 0; h < 2; ++h)
#pragma unroll
        for (int tp = 0; tp < 9; ++tp)
            A[h][tp] = *(const half8_t*)(wl + h * 8192 + tp * 16384);

    floatx4 bv;
#pragma unroll
    for (int r = 0; r < 4; ++r) bv[r] = bias[wvid * 16 + g * 4 + r];

    // ---- per-lane LDS byte offsets: F[cgf][kx][h] (verified formula) ----
    int F[4][3][2];
#pragma unroll
    for (int cgf = 0; cgf < 4; ++cgf)
#pragma unroll
        for (int kx = 0; kx < 3; ++kx)
#pragma unroll
            for (int h = 0; h < 2; ++h) {
                const int c = cgf * 16 + kx + ln;
                F[cgf][kx][h] = c * 128 + (((4 * h + g) ^ (c & 7)) << 4);
            }

    const char* xbase = (const char*)xp + (size_t)n * XP_NSTRIDE * 2 + (size_t)ow0 * 128;

#define STAGE(BUFSEL, IT)                                                              \
    {                                                                                  \
        const char* gt = xbase + (size_t)(band * 64 + (IT) * 4) * XP_RSTRIDE_B;        \
        const unsigned lb = (BUFSEL) * TILE_BYTES;                                     \
        _Pragma("unroll")                                                              \
        for (int p = 0; p < 6; ++p) {                                                  \
            const int u = p * 512 + tid;                                               \
            int row = (p * 512) / 528;                                                 \
            if (u >= (row + 1) * 528) row++;                                           \
            const int rem = u - row * 528;                                             \
            const int c = rem >> 3, s = rem & 7;                                       \
            gload_lds16(gt + (size_t)row * XP_RSTRIDE_B + c * 128 +                    \
                            (((s ^ (c & 7))) << 4),                                    \
                        xs + lb + ((unsigned)(p * 512 + (tid & ~63)) << 4));           \
        }                                                                              \
        if (tid < 96) {                                                                \
            const int rem = 432 + tid;                                                 \
            const int c = rem >> 3, s = rem & 7;                                       \
            const int4 v = *(const int4*)(gt + (size_t)5 * XP_RSTRIDE_B + c * 128 +    \
                                          ((s ^ (c & 7)) << 4));                       \
            *(int4*)(xs + lb + (unsigned)(3072 + tid) * 16) = v;                       \
        }                                                                              \
    }

    STAGE(0, 0);
    asm volatile("s_waitcnt vmcnt(0) lgkmcnt(0)" ::: "memory");
    __builtin_amdgcn_s_barrier();
    __builtin_amdgcn_sched_barrier(0);

    int cur = 0;
#pragma unroll 1
    for (int it = 0; it < 16; ++it) {
        // Issue next-tile staging FIRST (oldest vmem ops -> drained by counted vmcnt).
        if (it < 15) STAGE(cur ^ 1, it + 1);

        floatx4 acc[4][4];   // [rr][cgf]
#pragma unroll
        for (int rr = 0; rr < 4; ++rr)
#pragma unroll
            for (int cgf = 0; cgf < 4; ++cgf) acc[rr][cgf] = bv;

        const unsigned char* bb = xs + cur * TILE_BYTES;
#pragma unroll
        for (int kx = 0; kx < 3; ++kx)
#pragma unroll
            for (int h = 0; h < 2; ++h)
#pragma unroll
                for (int cgf = 0; cgf < 4; ++cgf) {
                    const unsigned char* bp = bb + F[cgf][kx][h];
                    half8_t bt[6];
#pragma unroll
                    for (int t = 0; t < 6; ++t)
                        bt[t] = *(const half8_t*)(bp + t * ROW_LDS);
#pragma unroll
                    for (int ky = 0; ky < 3; ++ky) {
                        const half8_t af = A[h][ky * 3 + kx];
#pragma unroll
                        for (int rr = 0; rr < 4; ++rr)
                            acc[rr][cgf] = __builtin_amdgcn_mfma_f32_16x16x32_f16(
                                af, bt[rr + ky], acc[rr][cgf], 0, 0, 0);
                    }
                }

        // ---- epilogue: per-wave LDS scratch -> full-line NT dwordx4 stores ----
        float* scr = &esc[wvid][0];
        const int orow0 = band * 64 + it * 4;
        float* obase = out + ((size_t)(n * 128 + wvid * 16)) * 65536 +
                       (size_t)orow0 * 256 + ow0;
#pragma unroll
        for (int rr = 0; rr < 4; ++rr) {
#pragma unroll
            for (int cgf = 0; cgf < 4; ++cgf)
#pragma unroll
                for (int r = 0; r < 4; ++r)
                    scr[(g * 4 + r) * 68 + cgf * 16 + ln] = acc[rr][cgf][r];
#pragma unroll
            for (int q = 0; q < 4; ++q) {
                const int co = q * 4 + g;
                const floatx4 v = *(const floatx4*)(scr + co * 68 + ln * 4);
                __builtin_nontemporal_store(
                    v, (floatx4*)(obase + (size_t)co * 65536 + rr * 256 + ln * 4));
            }
        }

        if (it < 15) {
            // Drain staging loads (oldest); leave this iter's 16 NT stores in flight.
            asm volatile("s_waitcnt vmcnt(16) lgkmcnt(0)" ::: "memory");
            __builtin_amdgcn_s_barrier();
            __builtin_amdgcn_sched_barrier(0);
        }
        cur ^= 1;
    }
#undef STAGE
}

// ---------- fallback (proven V2 fp32) if workspace too small ----------
__global__ __launch_bounds__(256) void Conv2d_fallback_kernel(
    const float* __restrict__ x, const float* __restrict__ w,
    const float* __restrict__ bias, float* __restrict__ out) {
    const int tx = threadIdx.x & 15, ty = threadIdx.x >> 4;
    const int ow0 = blockIdx.x * 64 + tx * 4;
    const int oh = blockIdx.y * 16 + ty;
    const int gg = blockIdx.z & 7, n = blockIdx.z >> 3;
    const int co = gg * 16;
    float acc[16][4];
#pragma unroll
    for (int c = 0; c < 16; ++c) {
        const float b = bias[co + c];
#pragma unroll
        for (int p = 0; p < 4; ++p) acc[c][p] = b;
    }
    const float* xn = x + (size_t)n * CIN * HH * WW;
    const float* wb = w + (size_t)co * CIN * 9;
    for (int ci = 0; ci < CIN; ++ci) {
        const float* xc = xn + (size_t)ci * HH * WW;
        float in[3][6];
#pragma unroll
        for (int ky = 0; ky < 3; ++ky) {
            const int iy = oh + ky - 1;
            if ((unsigned)iy < (unsigned)HH) {
                const float* row = xc + iy * WW;
                const float4 v = *(const float4*)(row + ow0);
                in[ky][1] = v.x; in[ky][2] = v.y; in[ky][3] = v.z; in[ky][4] = v.w;
                in[ky][0] = (ow0 > 0) ? row[ow0 - 1] : 0.0f;
                in[ky][5] = (ow0 < WW - 4) ? row[ow0 + 4] : 0.0f;
            } else {
#pragma unroll
                for (int j = 0; j < 6; ++j) in[ky][j] = 0.0f;
            }
        }
        const float* wc2 = wb + ci * 9;
#pragma unroll
        for (int c = 0; c < 16; ++c) {
            const float* wcc = wc2 + (size_t)c * CIN * 9;
#pragma unroll
            for (int ky = 0; ky < 3; ++ky)
#pragma unroll
                for (int kx = 0; kx < 3; ++kx) {
                    const float wv2 = wcc[ky * 3 + kx];
#pragma unroll
                    for (int p = 0; p < 4; ++p) acc[c][p] += in[ky][kx + p] * wv2;
                }
        }
    }
    const size_t hw = (size_t)HH * WW;
    float* ob = out + ((size_t)n * COUT + co) * hw + (size_t)oh * WW + ow0;
#pragma unroll
    for (int c = 0; c < 16; ++c) {
        float4 v;
        v.x = acc[c][0]; v.y = acc[c][1]; v.z = acc[c][2]; v.w = acc[c][3];
        *(float4*)(ob + (size_t)c * hw) = v;
    }
}

extern "C" void kernel_launch(void* const* d_in, const int* in_sizes, int n_in,
                              void* d_out, int out_size, void* d_ws, size_t ws_size,
                              hipStream_t stream) {
    const float* x = (const float*)d_in[0];
    const float* w = (const float*)d_in[1];
    const float* b = (const float*)d_in[2];
    float* out = (float*)d_out;

    const size_t xp_bytes = (size_t)NB * XP_NSTRIDE * 2;      // 136.3 MB
    const size_t wt_bytes = (size_t)9 * 8 * 128 * 8 * 2;      // 144 KiB

    if (ws_size >= xp_bytes + wt_bytes) {
        char* ws = (char*)d_ws;
        _Float16* xp = (_Float16*)ws;
        _Float16* w_t = (_Float16*)(ws + xp_bytes);
        Conv2d_wprep_kernel<<<dim3(288), 256, 0, stream>>>(w, w_t);
        Conv2d_xpad_zero_kernel<<<dim3(33, 16), 256, 0, stream>>>(xp);
        Conv2d_xprep_kernel<<<dim3(2, 256, 16), 256, 0, stream>>>(x, xp);
        Conv2dManual_77695958385099_kernel<<<dim3(4, 4, 16), 512, 0, stream>>>(
            xp, w_t, b, out);
    } else {
        dim3 grid(WW / 64, HH / 16, NB * (COUT / 16));
        Conv2d_fallback_kernel<<<grid, 256, 0, stream>>>(x, w, b, out);
    }
}